// Round 2
// baseline (963.101 us; speedup 1.0000x reference)
//
#include <hip/hip_runtime.h>
#include <hip/hip_fp16.h>
#include <stdint.h>

// Problem: B=4, S=2048, IN=4096, OUT=12288
//   x      : const float*  (fp16 promoted)   [8192][4096]
//   w_q    : const int*    (int8 in int32)   [12288][4096]
//   w_scale: const float*  [12288]
//   bias   : const float*  (fp16 promoted)   [12288]
//   out    : float*        [8192][12288]
#define M_TOK 8192
#define K_IN  4096
#define N_OUT 12288

typedef int v4i_t __attribute__((ext_vector_type(4)));

// async global->LDS, 16B/lane. LDS dest = wave-uniform base + lane*16 (HW).
__device__ __forceinline__ void load_lds16(const void* g, void* l) {
    __builtin_amdgcn_global_load_lds(
        (const __attribute__((address_space(1))) unsigned int*)g,
        (__attribute__((address_space(3))) unsigned int*)l, 16, 0, 0);
}

// ---------------- fused: pack w (int32->int8) + per-token dynamic quant ----------------
// blocks [0, PACK_BLOCKS): grid-stride pack.  blocks [PACK_BLOCKS, +8192): quant one token each.
#define PACK_BLOCKS 2048
#define PACK_ITERS  24   // PACK_BLOCKS*256*PACK_ITERS == N_OUT*K_IN/4 == 12582912

__global__ __launch_bounds__(256) void prep_kernel(
    const int* __restrict__ wsrc, uint32_t* __restrict__ wdst,
    const float* __restrict__ x, int8_t* __restrict__ xq, float* __restrict__ xs) {
    const int tid = threadIdx.x;
    const int bid = blockIdx.x;
    if (bid < PACK_BLOCKS) {
        size_t i = (size_t)bid * 256 + tid;
#pragma unroll
        for (int it = 0; it < PACK_ITERS; ++it, i += (size_t)PACK_BLOCKS * 256) {
            const int4 v = ((const int4*)wsrc)[i];     // lane-contiguous 16B loads
            wdst[i] = (uint32_t)(uint8_t)(int8_t)v.x   // lane-contiguous 4B stores
                    | ((uint32_t)(uint8_t)(int8_t)v.y << 8)
                    | ((uint32_t)(uint8_t)(int8_t)v.z << 16)
                    | ((uint32_t)(uint8_t)(int8_t)v.w << 24);
        }
        return;
    }
    // ---- quant: coalesced float4 reads (lane-contiguous), exact ref numerics ----
    const int token = bid - PACK_BLOCKS;
    const float4* src = (const float4*)(x + (size_t)token * K_IN);
    float v[16];
#pragma unroll
    for (int c = 0; c < 4; ++c) {
        float4 p = src[c * 256 + tid];
        v[c * 4 + 0] = p.x; v[c * 4 + 1] = p.y;
        v[c * 4 + 2] = p.z; v[c * 4 + 3] = p.w;
    }
    float amax = 0.f;
#pragma unroll
    for (int i = 0; i < 16; ++i) amax = fmaxf(amax, fabsf(v[i]));
#pragma unroll
    for (int off = 32; off >= 1; off >>= 1)
        amax = fmaxf(amax, __shfl_xor(amax, off));
    __shared__ float wmax[4];
    const int wave = tid >> 6, lane = tid & 63;
    if (lane == 0) wmax[wave] = amax;
    __syncthreads();
    amax = fmaxf(fmaxf(wmax[0], wmax[1]), fmaxf(wmax[2], wmax[3]));
    const float scale = fmaxf(amax, 1e-6f) / 127.0f;  // exact div, matches np
    if (tid == 0) xs[token] = scale;

    uint32_t* dst = (uint32_t*)(xq + (size_t)token * K_IN);
#pragma unroll
    for (int c = 0; c < 4; ++c) {
        uint32_t w = 0;
#pragma unroll
        for (int e = 0; e < 4; ++e) {
            float r = rintf(v[c * 4 + e] / scale);   // half-to-even, matches jnp.round
            r = fminf(fmaxf(r, -128.f), 127.f);
            w |= (uint32_t)(uint8_t)(int8_t)(int)r << (8 * e);
        }
        dst[c * 256 + tid] = w;  // word c*256+tid == elements 4*(c*256+tid)+e  (exact)
    }
}

// ---------------- int8 GEMM: 256x256 tile, BK=128B, 8 waves, 4-phase counted-vmcnt ----------------
// LDS 128KiB: A[2buf][2kk][256 rows][64B] at 0, B same at 65536.
// Half-tile h: tile=h>>2, role=h&3 {A-k0,B-k0,A-k1,B-k1}; staged at phase h-6 (1/phase),
// 2 global_load_lds (8KB each, rows 0-127 / 128-255).  Steady state: 12 loads in flight.
// vmcnt ledger (2 loads/half):  end p1 drains kk1 of T (leave h4T+4..+7 -> vmcnt(8));
//                              end p3 drains kk0 of T+1 (leave h4T+6..+9 -> vmcnt(8)).
// Tail: T=30 p3 -> vmcnt(4); T=31 p1 -> vmcnt(0). Slot re-stage always >= 1 barrier after last read.
// Swizzle (rule 21, verified r1: BANK_CONFLICT=0): linear dest + involution source + same on read.
//   LDS cell (row l, granule c16) holds global (row swap02(l), col c16 ^ ((l>>1)&3)).
// Block->tile mapping (r2, LLC/L2 locality): XCD x = bid&7 owns by-band x*4..x*4+3; within the
// XCD, 6 groups of 32 resident blocks, each a 4(by) x 8(bx) rectangle -> concurrent set
// 4 A-tiles + 8 B-tiles = 12 MB/XCD; A-band LLC-resident across groups; bx lock-step across XCDs.
__global__ __launch_bounds__(512, 2) void gemm_kernel(
    const int8_t* __restrict__ xq, const float* __restrict__ xs,
    const int8_t* __restrict__ wq, const float* __restrict__ wscale,
    const float* __restrict__ bias, float* __restrict__ out) {
    extern __shared__ char smem[];

    const int tid  = threadIdx.x;
    const int wid  = tid >> 6, lane = tid & 63;
    const int wr   = wid >> 2, wc = wid & 3;   // 2M x 4N waves; wave output 128x64

    // XCD-chunked bijective mapping: bid <-> (x, g, r) <-> (by, bx)
    const int bid = blockIdx.x;
    const int xcd = bid & 7;
    const int s   = bid >> 3;        // 0..191
    const int g   = s >> 5;          // 0..5
    const int r_  = s & 31;
    const int by  = xcd * 4 + (r_ & 3);
    const int bx  = g * 8 + (r_ >> 2);
    const int m0  = by * 256, n0 = bx * 256;

    const int8_t* Ag = xq + (size_t)m0 * K_IN;
    const int8_t* Bg = wq + (size_t)n0 * K_IN;

    // staging source pre-swizzle: row bit0<->bit2 swap + granule XOR (l>>1)&3
    const int rl = (lane >> 2) & 15;
    const int rg = (rl & 0xA) | ((rl & 1) << 2) | ((rl >> 2) & 1);
    const size_t rowByte = (size_t)(wid * 16 + rg) * K_IN;
    const int gsw16 = ((lane & 3) ^ ((lane >> 3) & 3)) << 4;

    // fragment read offset: A[m=lane&15][k=(lane>>4)*16+j]; apply same involution
    const int fr = lane & 15, fq = lane >> 4;
    const int sfr = (fr & 0xA) | ((fr & 1) << 2) | ((fr >> 2) & 1);
    const int frOff = sfr * 64 + (((fq ^ (sfr >> 1)) & 3) << 4);

    auto stage_half = [&](int h) {
        const int th = h >> 2, r = h & 3;
        const int isB = r & 1, kk = r >> 1;
        const int8_t* G = isB ? Bg : Ag;
        char* lb = smem + (isB << 16) + ((((th & 1) << 1) | kk) << 14) + (wid << 10);
        const int8_t* g0 = G + rowByte + th * 128 + (kk << 6) + gsw16;
        load_lds16(g0, lb);
        load_lds16(g0 + (size_t)128 * K_IN, lb + 8192);
    };

    v4i_t acc[8][4] = {};

    // prologue: halves 0..5 (tile0 all + tile1 kk0); drain tile0-kk0 -> vmcnt(8)
#pragma unroll
    for (int h = 0; h < 6; ++h) stage_half(h);
    asm volatile("s_waitcnt vmcnt(8)" ::: "memory");
    __builtin_amdgcn_s_barrier();
    __builtin_amdgcn_sched_barrier(0);

    for (int T = 0; T < 32; ++T) {
        const int b   = T & 1;
        const int A0o = b << 15, A1o = A0o + 16384;
        const int B0o = 65536 + A0o, B1o = 65536 + A1o;
        const int h0  = 4 * T + 6;
        const int ab  = (wr << 13) + frOff;
        const int bb  = (wc << 12) + frOff;
        v4i_t af[4], bf[4];

        // ---- phase 0: kk0, i=0..3 (reads B kk0 too) ----
#pragma unroll
        for (int j = 0; j < 4; ++j) bf[j] = *(const v4i_t*)(smem + B0o + bb + (j << 10));
#pragma unroll
        for (int i = 0; i < 4; ++i) af[i] = *(const v4i_t*)(smem + A0o + ab + (i << 10));
        if (h0 < 128) stage_half(h0);
        __builtin_amdgcn_s_barrier();
        asm volatile("s_waitcnt lgkmcnt(0)" ::: "memory");
        __builtin_amdgcn_sched_barrier(0);
        __builtin_amdgcn_s_setprio(1);
#pragma unroll
        for (int i = 0; i < 4; ++i)
#pragma unroll
            for (int j = 0; j < 4; ++j)
                acc[i][j] = __builtin_amdgcn_mfma_i32_16x16x64_i8(af[i], bf[j], acc[i][j], 0, 0, 0);
        __builtin_amdgcn_s_setprio(0);
        __builtin_amdgcn_s_barrier();
        __builtin_amdgcn_sched_barrier(0);

        // ---- phase 1: kk0, i=4..7 (bf cached) ----
#pragma unroll
        for (int i = 0; i < 4; ++i) af[i] = *(const v4i_t*)(smem + A0o + ab + ((i + 4) << 10));
        if (h0 + 1 < 128) stage_half(h0 + 1);
        __builtin_amdgcn_s_barrier();
        asm volatile("s_waitcnt lgkmcnt(0)" ::: "memory");
        __builtin_amdgcn_sched_barrier(0);
        __builtin_amdgcn_s_setprio(1);
#pragma unroll
        for (int i = 0; i < 4; ++i)
#pragma unroll
            for (int j = 0; j < 4; ++j)
                acc[i + 4][j] = __builtin_amdgcn_mfma_i32_16x16x64_i8(af[i], bf[j], acc[i + 4][j], 0, 0, 0);
        __builtin_amdgcn_s_setprio(0);
        if (T < 31) asm volatile("s_waitcnt vmcnt(8)" ::: "memory");  // drain kk1 of T
        else        asm volatile("s_waitcnt vmcnt(0)" ::: "memory");
        __builtin_amdgcn_s_barrier();
        __builtin_amdgcn_sched_barrier(0);

        // ---- phase 2: kk1, i=0..3 (reads B kk1) ----
#pragma unroll
        for (int j = 0; j < 4; ++j) bf[j] = *(const v4i_t*)(smem + B1o + bb + (j << 10));
#pragma unroll
        for (int i = 0; i < 4; ++i) af[i] = *(const v4i_t*)(smem + A1o + ab + (i << 10));
        if (h0 + 2 < 128) stage_half(h0 + 2);
        __builtin_amdgcn_s_barrier();
        asm volatile("s_waitcnt lgkmcnt(0)" ::: "memory");
        __builtin_amdgcn_sched_barrier(0);
        __builtin_amdgcn_s_setprio(1);
#pragma unroll
        for (int i = 0; i < 4; ++i)
#pragma unroll
            for (int j = 0; j < 4; ++j)
                acc[i][j] = __builtin_amdgcn_mfma_i32_16x16x64_i8(af[i], bf[j], acc[i][j], 0, 0, 0);
        __builtin_amdgcn_s_setprio(0);
        __builtin_amdgcn_s_barrier();
        __builtin_amdgcn_sched_barrier(0);

        // ---- phase 3: kk1, i=4..7 ----
#pragma unroll
        for (int i = 0; i < 4; ++i) af[i] = *(const v4i_t*)(smem + A1o + ab + ((i + 4) << 10));
        if (h0 + 3 < 128) stage_half(h0 + 3);
        __builtin_amdgcn_s_barrier();
        asm volatile("s_waitcnt lgkmcnt(0)" ::: "memory");
        __builtin_amdgcn_sched_barrier(0);
        __builtin_amdgcn_s_setprio(1);
#pragma unroll
        for (int i = 0; i < 4; ++i)
#pragma unroll
            for (int j = 0; j < 4; ++j)
                acc[i + 4][j] = __builtin_amdgcn_mfma_i32_16x16x64_i8(af[i], bf[j], acc[i + 4][j], 0, 0, 0);
        __builtin_amdgcn_s_setprio(0);
        if (T < 30)       asm volatile("s_waitcnt vmcnt(8)" ::: "memory");  // drain kk0 of T+1
        else if (T == 30) asm volatile("s_waitcnt vmcnt(4)" ::: "memory");
        __builtin_amdgcn_s_barrier();
        __builtin_amdgcn_sched_barrier(0);
    }

    // epilogue: C/D layout col=lane&15, row=(lane>>4)*4+reg (verified in prior rounds)
    const int col = lane & 15, rq = lane >> 4;
#pragma unroll
    for (int i = 0; i < 8; ++i) {
        const int mb = m0 + wr * 128 + i * 16 + rq * 4;
        float xsv[4];
#pragma unroll
        for (int r = 0; r < 4; ++r) xsv[r] = xs[mb + r];
#pragma unroll
        for (int j = 0; j < 4; ++j) {
            const int n = n0 + wc * 64 + j * 16 + col;
            const float ws = wscale[n];
            const float bv = bias[n];
#pragma unroll
            for (int r = 0; r < 4; ++r) {
                float o = (float)acc[i][j][r] * xsv[r] * ws + bv;
                o = __half2float(__float2half(o));   // match ref's final .astype(float16)
                out[(size_t)(mb + r) * N_OUT + n] = o;
            }
        }
    }
}

extern "C" void kernel_launch(void* const* d_in, const int* in_sizes, int n_in,
                              void* d_out, int out_size, void* d_ws, size_t ws_size,
                              hipStream_t stream) {
    const float* x      = (const float*)d_in[0];
    const int*   wq32   = (const int*)d_in[1];
    const float* wscale = (const float*)d_in[2];
    const float* bias   = (const float*)d_in[3];
    float* out = (float*)d_out;

    int8_t* xq  = (int8_t*)d_ws;                                            // 32 MiB
    float*  xs  = (float*)((char*)d_ws + (size_t)M_TOK * K_IN);             // 32 KiB
    int8_t* wq8 = (int8_t*)((char*)d_ws + (size_t)M_TOK * K_IN + 65536);    // 48 MiB

    static bool attrDone = false;
    if (!attrDone) {
        (void)hipFuncSetAttribute((const void*)gemm_kernel,
                                  hipFuncAttributeMaxDynamicSharedMemorySize, 131072);
        attrDone = true;
    }

    prep_kernel<<<PACK_BLOCKS + M_TOK, 256, 0, stream>>>(wq32, (uint32_t*)wq8, x, xq, xs);

    gemm_kernel<<<dim3(1536), dim3(512), 131072, stream>>>(xq, xs, wq8, wscale, bias, out);
}

// Round 3
// 943.221 us; speedup vs baseline: 1.0211x; 1.0211x over previous
//
#include <hip/hip_runtime.h>
#include <hip/hip_fp16.h>
#include <stdint.h>

// Problem: B=4, S=2048, IN=4096, OUT=12288
//   x      : const float*  (fp16 promoted)   [8192][4096]
//   w_q    : const int*    (int8 in int32)   [12288][4096]
//   w_scale: const float*  [12288]
//   bias   : const float*  (fp16 promoted)   [12288]
//   out    : float*        [8192][12288]
#define M_TOK 8192
#define K_IN  4096
#define N_OUT 12288

typedef int v4i_t __attribute__((ext_vector_type(4)));

// async global->LDS, 16B/lane. LDS dest = wave-uniform base + lane*16 (HW).
__device__ __forceinline__ void load_lds16(const void* g, void* l) {
    __builtin_amdgcn_global_load_lds(
        (const __attribute__((address_space(1))) unsigned int*)g,
        (__attribute__((address_space(3))) unsigned int*)l, 16, 0, 0);
}

// ---------------- fused: pack w (int32->int8) + per-token dynamic quant ----------------
#define PACK_BLOCKS 2048
#define PACK_ITERS  24   // PACK_BLOCKS*256*PACK_ITERS == N_OUT*K_IN/4 == 12582912

__global__ __launch_bounds__(256) void prep_kernel(
    const int* __restrict__ wsrc, uint32_t* __restrict__ wdst,
    const float* __restrict__ x, int8_t* __restrict__ xq, float* __restrict__ xs) {
    const int tid = threadIdx.x;
    const int bid = blockIdx.x;
    if (bid < PACK_BLOCKS) {
        size_t i = (size_t)bid * 256 + tid;
#pragma unroll
        for (int it = 0; it < PACK_ITERS; ++it, i += (size_t)PACK_BLOCKS * 256) {
            const int4 v = ((const int4*)wsrc)[i];
            wdst[i] = (uint32_t)(uint8_t)(int8_t)v.x
                    | ((uint32_t)(uint8_t)(int8_t)v.y << 8)
                    | ((uint32_t)(uint8_t)(int8_t)v.z << 16)
                    | ((uint32_t)(uint8_t)(int8_t)v.w << 24);
        }
        return;
    }
    const int token = bid - PACK_BLOCKS;
    const float4* src = (const float4*)(x + (size_t)token * K_IN);
    float v[16];
#pragma unroll
    for (int c = 0; c < 4; ++c) {
        float4 p = src[c * 256 + tid];
        v[c * 4 + 0] = p.x; v[c * 4 + 1] = p.y;
        v[c * 4 + 2] = p.z; v[c * 4 + 3] = p.w;
    }
    float amax = 0.f;
#pragma unroll
    for (int i = 0; i < 16; ++i) amax = fmaxf(amax, fabsf(v[i]));
#pragma unroll
    for (int off = 32; off >= 1; off >>= 1)
        amax = fmaxf(amax, __shfl_xor(amax, off));
    __shared__ float wmax[4];
    const int wave = tid >> 6, lane = tid & 63;
    if (lane == 0) wmax[wave] = amax;
    __syncthreads();
    amax = fmaxf(fmaxf(wmax[0], wmax[1]), fmaxf(wmax[2], wmax[3]));
    const float scale = fmaxf(amax, 1e-6f) / 127.0f;  // exact div, matches np
    if (tid == 0) xs[token] = scale;

    uint32_t* dst = (uint32_t*)(xq + (size_t)token * K_IN);
#pragma unroll
    for (int c = 0; c < 4; ++c) {
        uint32_t w = 0;
#pragma unroll
        for (int e = 0; e < 4; ++e) {
            float r = rintf(v[c * 4 + e] / scale);   // half-to-even, matches jnp.round
            r = fminf(fmaxf(r, -128.f), 127.f);
            w |= (uint32_t)(uint8_t)(int8_t)(int)r << (8 * e);
        }
        dst[c * 256 + tid] = w;
    }
}

// ---------------- int8 GEMM: 256x256 tile, BK=128B, 8 waves, 1-barrier/phase counted-vmcnt ----------
// LDS 128KiB: A[2buf][2kk][256 rows][64B] at 0, B same at 65536. Half-tile h: tile th=h>>2,
// role h&3 = {A-k0,B-k0,A-k1,B-k1}; STAGED AT PHASE h-5 (prologue = halves 0..4, vmcnt(6)).
// Phase (4T+PH): [reads][stage h=4T+5+PH][s_barrier][lgkm(0)][16 MFMA][ckpt].
// Ledger (re-derived for 1-barrier):
//  * overwrite-vs-read: stage(h) at h-5 overwrites data last lgkm-completed at phase h-7;
//    stager passed barrier(h-6) => all waves' lgkm(h-7) done. >=1 barrier gap, all 4 streams. SAFE.
//  * ckpt end-p0: guards halves 4T+2,+3 (read p2/p3). Newer ops = stages at phases 4T-1,4T
//    = 4 loads -> vmcnt(4). Consumer reads_p2 follow barrier(p1); every wave's ckpt precedes its
//    barrier(p1) arrival => producer drains globally visible. T=31 -> vmcnt(0) (no newer stages).
//  * ckpt end-p2: guards halves 4T+4,+5 (read p0/p1 of T+1). Newer = stages at 4T+1,4T+2
//    = 4 loads -> vmcnt(4). T=31: no consumer, omitted.
//  * cover: staged h-5, needed h => ~5 phases ≈ 5000 cyc >> 900-cyc HBM miss.
// Swizzle (verified r1: BANK_CONFLICT=0): linear LDS dest + involution source + same on read.
// Block->tile map (verified r2: FETCH 825->296MB): XCD band by=xcd*4+(r&3), bx=g*8+(r>>2).
__global__ __launch_bounds__(512, 2) void gemm_kernel(
    const int8_t* __restrict__ xq, const float* __restrict__ xs,
    const int8_t* __restrict__ wq, const float* __restrict__ wscale,
    const float* __restrict__ bias, float* __restrict__ out) {
    extern __shared__ char smem[];

    const int tid  = threadIdx.x;
    const int wid  = tid >> 6, lane = tid & 63;
    const int wr   = wid >> 2, wc = wid & 3;   // 2M x 4N waves; wave output 128x64

    const int bid = blockIdx.x;
    const int xcd = bid & 7;
    const int s   = bid >> 3;        // 0..191
    const int g   = s >> 5;          // 0..5
    const int r_  = s & 31;
    const int by  = xcd * 4 + (r_ & 3);
    const int bx  = g * 8 + (r_ >> 2);
    const int m0  = by * 256, n0 = bx * 256;

    const int8_t* Ag = xq + (size_t)m0 * K_IN;
    const int8_t* Bg = wq + (size_t)n0 * K_IN;

    // staging source pre-swizzle: row bit0<->bit2 swap + granule XOR (l>>1)&3
    const int rl = (lane >> 2) & 15;
    const int rg = (rl & 0xA) | ((rl & 1) << 2) | ((rl >> 2) & 1);
    const size_t rowByte = (size_t)(wid * 16 + rg) * K_IN;
    const int gsw16 = ((lane & 3) ^ ((lane >> 3) & 3)) << 4;

    // fragment read offset: A[m=lane&15][k=(lane>>4)*16+j]; same involution
    const int fr = lane & 15, fq = lane >> 4;
    const int sfr = (fr & 0xA) | ((fr & 1) << 2) | ((fr >> 2) & 1);
    const int frOff = sfr * 64 + (((fq ^ (sfr >> 1)) & 3) << 4);

    auto stage_half = [&](int h) {
        const int th = h >> 2, r = h & 3;
        const int isB = r & 1, kk = r >> 1;
        const int8_t* G = isB ? Bg : Ag;
        char* lb = smem + (isB << 16) + ((((th & 1) << 1) | kk) << 14) + (wid << 10);
        const int8_t* g0 = G + rowByte + th * 128 + (kk << 6) + gsw16;
        load_lds16(g0, lb);
        load_lds16(g0 + (size_t)128 * K_IN, lb + 8192);
    };

    v4i_t acc[8][4] = {};

    // prologue: halves 0..4 (10 loads); drain h0,h1 -> vmcnt(6)
#pragma unroll
    for (int h = 0; h < 5; ++h) stage_half(h);
    asm volatile("s_waitcnt vmcnt(6)" ::: "memory");
    __builtin_amdgcn_sched_barrier(0);
    __builtin_amdgcn_s_barrier();
    __builtin_amdgcn_sched_barrier(0);

    v4i_t af[4], bf[4];

// one phase: PH in {0,1,2,3}; kk = PH>>1; i-offset = (PH&1)*4. LAST = (T==31).
#define PHASE(T_, PH_, LAST_)                                                          \
    {                                                                                  \
        const int kk_   = (PH_) >> 1;                                                  \
        const int slab_ = ((((T_) & 1) << 1) | kk_) << 14;                             \
        const int ioff_ = ((PH_) & 1) * 4;                                             \
        if (((PH_) & 1) == 0) {                                                        \
            _Pragma("unroll")                                                          \
            for (int j = 0; j < 4; ++j)                                                \
                bf[j] = *(const v4i_t*)(smem + 65536 + slab_ + (wc << 12) + frOff + (j << 10)); \
        }                                                                              \
        _Pragma("unroll")                                                              \
        for (int i = 0; i < 4; ++i)                                                    \
            af[i] = *(const v4i_t*)(smem + slab_ + (wr << 13) + frOff + ((ioff_ + i) << 10)); \
        const int hs_ = 4 * (T_) + 5 + (PH_);                                          \
        if (hs_ < 128) stage_half(hs_);                                                \
        __builtin_amdgcn_sched_barrier(0);                                             \
        __builtin_amdgcn_s_barrier();                                                  \
        asm volatile("s_waitcnt lgkmcnt(0)" ::: "memory");                             \
        __builtin_amdgcn_sched_barrier(0);                                             \
        __builtin_amdgcn_s_setprio(1);                                                 \
        _Pragma("unroll")                                                              \
        for (int i = 0; i < 4; ++i)                                                    \
            _Pragma("unroll")                                                          \
            for (int j = 0; j < 4; ++j)                                                \
                acc[ioff_ + i][j] =                                                    \
                    __builtin_amdgcn_mfma_i32_16x16x64_i8(af[i], bf[j], acc[ioff_ + i][j], 0, 0, 0); \
        __builtin_amdgcn_s_setprio(0);                                                 \
        if ((PH_) == 0) {                                                              \
            if (LAST_) asm volatile("s_waitcnt vmcnt(0)" ::: "memory");                \
            else       asm volatile("s_waitcnt vmcnt(4)" ::: "memory");                \
            __builtin_amdgcn_sched_barrier(0);                                         \
        }                                                                              \
        if ((PH_) == 2 && !(LAST_)) {                                                  \
            asm volatile("s_waitcnt vmcnt(4)" ::: "memory");                           \
            __builtin_amdgcn_sched_barrier(0);                                         \
        }                                                                              \
    }

    for (int T = 0; T < 31; ++T) {
        PHASE(T, 0, false)
        PHASE(T, 1, false)
        PHASE(T, 2, false)
        PHASE(T, 3, false)
    }
    // peeled T=31 tail
    PHASE(31, 0, true)
    PHASE(31, 1, true)
    PHASE(31, 2, true)
    PHASE(31, 3, true)
#undef PHASE

    // epilogue: C/D layout col=lane&15, row=(lane>>4)*4+reg (verified in prior rounds)
    const int col = lane & 15, rq = lane >> 4;
#pragma unroll
    for (int i = 0; i < 8; ++i) {
        const int mb = m0 + wr * 128 + i * 16 + rq * 4;
        float xsv[4];
#pragma unroll
        for (int r = 0; r < 4; ++r) xsv[r] = xs[mb + r];
#pragma unroll
        for (int j = 0; j < 4; ++j) {
            const int n = n0 + wc * 64 + j * 16 + col;
            const float ws = wscale[n];
            const float bv = bias[n];
#pragma unroll
            for (int r = 0; r < 4; ++r) {
                float o = (float)acc[i][j][r] * xsv[r] * ws + bv;
                o = __half2float(__float2half(o));   // match ref's final .astype(float16)
                out[(size_t)(mb + r) * N_OUT + n] = o;
            }
        }
    }
}

extern "C" void kernel_launch(void* const* d_in, const int* in_sizes, int n_in,
                              void* d_out, int out_size, void* d_ws, size_t ws_size,
                              hipStream_t stream) {
    const float* x      = (const float*)d_in[0];
    const int*   wq32   = (const int*)d_in[1];
    const float* wscale = (const float*)d_in[2];
    const float* bias   = (const float*)d_in[3];
    float* out = (float*)d_out;

    int8_t* xq  = (int8_t*)d_ws;                                            // 32 MiB
    float*  xs  = (float*)((char*)d_ws + (size_t)M_TOK * K_IN);             // 32 KiB
    int8_t* wq8 = (int8_t*)((char*)d_ws + (size_t)M_TOK * K_IN + 65536);    // 48 MiB

    static bool attrDone = false;
    if (!attrDone) {
        (void)hipFuncSetAttribute((const void*)gemm_kernel,
                                  hipFuncAttributeMaxDynamicSharedMemorySize, 131072);
        attrDone = true;
    }

    prep_kernel<<<PACK_BLOCKS + M_TOK, 256, 0, stream>>>(wq32, (uint32_t*)wq8, x, xq, xs);

    gemm_kernel<<<dim3(1536), dim3(512), 131072, stream>>>(xq, xs, wq8, wscale, bias, out);
}